// Round 1
// baseline (773.920 us; speedup 1.0000x reference)
//
#include <hip/hip_runtime.h>

#define AS1 __attribute__((address_space(1)))
#define AS3 __attribute__((address_space(3)))

typedef __attribute__((ext_vector_type(8))) short short8;
typedef __attribute__((ext_vector_type(4))) float f32x4;

static __device__ __forceinline__ unsigned short f2bf(float f) {
    unsigned u = __builtin_bit_cast(unsigned, f);
    u += 0x7FFFu + ((u >> 16) & 1u);
    return (unsigned short)(u >> 16);
}

// ---------------- conversion kernels ----------------

__global__ void cvt_bf16_kernel(const float* __restrict__ in,
                                unsigned short* __restrict__ out, int n8) {
    int i = blockIdx.x * blockDim.x + threadIdx.x;
    int stride = gridDim.x * blockDim.x;
    for (; i < n8; i += stride) {
        const float4* p = (const float4*)in + 2 * (size_t)i;
        float4 a = p[0], b = p[1];
        short8 o;
        o[0] = f2bf(a.x); o[1] = f2bf(a.y); o[2] = f2bf(a.z); o[3] = f2bf(a.w);
        o[4] = f2bf(b.x); o[5] = f2bf(b.y); o[6] = f2bf(b.z); o[7] = f2bf(b.w);
        *(short8*)(out + 8 * (size_t)i) = o;
    }
}

// out[m,k] = bf16(wa[m,k] * wb[k]),  K = 512 fixed
__global__ void wab_kernel(const float* __restrict__ wa, const float* __restrict__ wb,
                           unsigned short* __restrict__ out, int n8) {
    int i = blockIdx.x * blockDim.x + threadIdx.x;
    int stride = gridDim.x * blockDim.x;
    for (; i < n8; i += stride) {
        int base = i * 8;
        int k = base & 511;
        const float4* pa = (const float4*)(wa + base);
        const float4* pb = (const float4*)(wb + k);
        float4 a0 = pa[0], a1 = pa[1], b0 = pb[0], b1 = pb[1];
        short8 o;
        o[0] = f2bf(a0.x * b0.x); o[1] = f2bf(a0.y * b0.y);
        o[2] = f2bf(a0.z * b0.z); o[3] = f2bf(a0.w * b0.w);
        o[4] = f2bf(a1.x * b1.x); o[5] = f2bf(a1.y * b1.y);
        o[6] = f2bf(a1.z * b1.z); o[7] = f2bf(a1.w * b1.w);
        *(short8*)(out + 8 * (size_t)i) = o;
    }
}

// wc[512][N] -> out[N][512] bf16 (transpose)
__global__ void wcT_kernel(const float* __restrict__ wc,
                           unsigned short* __restrict__ out, int N) {
    int i = blockIdx.x * blockDim.x + threadIdx.x;
    int total = N * 512;
    int stride = gridDim.x * blockDim.x;
    for (; i < total; i += stride) {
        int n = i >> 9, k = i & 511;
        out[i] = f2bf(wc[(size_t)k * N + n]);
    }
}

__global__ void bih_kernel(const float* __restrict__ b1, const float* __restrict__ ib1,
                           float* __restrict__ out) {
    int i = blockIdx.x * blockDim.x + threadIdx.x;
    if (i < 1536) out[i] = (i < 1024) ? b1[i] : ib1[i - 1024];
}

__global__ void hinit_kernel(unsigned short* __restrict__ hbf, float* __restrict__ hfp) {
    int i = blockIdx.x * blockDim.x + threadIdx.x;
    if (i < 65536) { hbf[i] = 0; hfp[i] = 0.f; }
}

// ---------------- NT GEMM: C[M,N] = A[M,K](bf16) * B[N,K]^T(bf16) (+bias) ----------------
// 128x128 tile, BK=64, 256 threads (2x2 waves of 64x64), 16x16x32 bf16 MFMA, fp32 accum.

template <typename OutT, bool BIAS>
__global__ __launch_bounds__(256) void gemm_nt_kernel(
    const unsigned short* __restrict__ A, const unsigned short* __restrict__ B,
    OutT* __restrict__ C, const float* __restrict__ bias, int K, int ldC) {
    __shared__ __align__(16) unsigned short As[128 * 64];
    __shared__ __align__(16) unsigned short Bs[128 * 64];
    const int tid = threadIdx.x;
    const int wave = tid >> 6, lane = tid & 63;
    const long bm = (long)blockIdx.x * 128, bn = (long)blockIdx.y * 128;
    const int wr = (wave >> 1) * 64, wc = (wave & 1) * 64;
    f32x4 acc[4][4] = {};

    const int srow = tid >> 3;          // staging row within 32-row chunk
    const int scol = (tid & 7) * 8;     // staging col (bf16 elements)
    const unsigned short* Ag = A + bm * K + scol;
    const unsigned short* Bg = B + bn * K + scol;

    for (int kt = 0; kt < K; kt += 64) {
        __syncthreads();
#pragma unroll
        for (int i = 0; i < 4; ++i) {
            __builtin_amdgcn_global_load_lds(
                (const AS1 void*)(Ag + (long)(i * 32 + srow) * K + kt),
                (AS3 void*)(As + i * 2048 + wave * 512), 16, 0, 0);
        }
#pragma unroll
        for (int i = 0; i < 4; ++i) {
            __builtin_amdgcn_global_load_lds(
                (const AS1 void*)(Bg + (long)(i * 32 + srow) * K + kt),
                (AS3 void*)(Bs + i * 2048 + wave * 512), 16, 0, 0);
        }
        __syncthreads();
#pragma unroll
        for (int kk = 0; kk < 2; ++kk) {
            const int ko = kk * 32 + (lane >> 4) * 8;
            short8 af[4], bfr[4];
#pragma unroll
            for (int mi = 0; mi < 4; ++mi)
                af[mi] = *(const short8*)(As + (wr + mi * 16 + (lane & 15)) * 64 + ko);
#pragma unroll
            for (int ni = 0; ni < 4; ++ni)
                bfr[ni] = *(const short8*)(Bs + (wc + ni * 16 + (lane & 15)) * 64 + ko);
#pragma unroll
            for (int mi = 0; mi < 4; ++mi)
#pragma unroll
                for (int ni = 0; ni < 4; ++ni)
                    acc[mi][ni] = __builtin_amdgcn_mfma_f32_16x16x32_bf16(
                        af[mi], bfr[ni], acc[mi][ni], 0, 0, 0);
        }
    }

    const int rbase = (lane >> 4) * 4;
    const int cbase = lane & 15;
#pragma unroll
    for (int mi = 0; mi < 4; ++mi) {
#pragma unroll
        for (int ni = 0; ni < 4; ++ni) {
            long gc = bn + wc + ni * 16 + cbase;
            float bv = BIAS ? bias[gc] : 0.f;
#pragma unroll
            for (int j = 0; j < 4; ++j) {
                long gr = bm + wr + mi * 16 + rbase + j;
                float v = acc[mi][ni][j] + bv;
                if constexpr (sizeof(OutT) == 2)
                    C[gr * ldC + gc] = (OutT)f2bf(v);
                else
                    C[gr * ldC + gc] = v;
            }
        }
    }
}

// ---------------- GRU step kernel ----------------
// One wave per block. Block (bx,by): batch rows [bx*16, +16), h-cols [by*32, +32).
// gh = h(bf16) @ whh^T for the 3 gate slices, then fused gate update.

__global__ __launch_bounds__(64) void gru_step_kernel(
    const unsigned short* __restrict__ hbf, const float* __restrict__ hfp,
    unsigned short* __restrict__ hbf_n, float* __restrict__ hfp_n,
    const unsigned short* __restrict__ whh, const float* __restrict__ bhh,
    const float* __restrict__ gi, const float* __restrict__ gf,
    float* __restrict__ out, float* __restrict__ hT, int t) {
    const int lane = threadIdx.x;
    const int r0 = blockIdx.x * 16;
    const int c0 = blockIdx.y * 32;
    f32x4 acc[3][2] = {};

    const int arow = r0 + (lane & 15);
    const int koff = (lane >> 4) * 8;

#pragma unroll 4
    for (int kk = 0; kk < 512; kk += 32) {
        short8 a = *(const short8*)(hbf + (size_t)arow * 512 + kk + koff);
#pragma unroll
        for (int g = 0; g < 3; ++g) {
#pragma unroll
            for (int ci = 0; ci < 2; ++ci) {
                const unsigned short* bp =
                    whh + (size_t)(g * 512 + c0 + ci * 16 + (lane & 15)) * 512 + kk + koff;
                short8 b = *(const short8*)bp;
                acc[g][ci] = __builtin_amdgcn_mfma_f32_16x16x32_bf16(a, b, acc[g][ci], 0, 0, 0);
            }
        }
    }

    const int rb = (lane >> 4) * 4;
#pragma unroll
    for (int ci = 0; ci < 2; ++ci) {
        int hc = c0 + ci * 16 + (lane & 15);
        float br = bhh[hc], bz = bhh[512 + hc], bn = bhh[1024 + hc];
#pragma unroll
        for (int j = 0; j < 4; ++j) {
            int bb = r0 + rb + j;
            size_t grow = (size_t)(bb * 64 + t);
            float ir  = gi[grow * 1536 + hc];
            float ii  = gi[grow * 1536 + 512 + hc];
            float inn = gi[grow * 1536 + 1024 + hc];
            float fr  = gf[grow * 1024 + hc];
            float fi  = gf[grow * 1024 + 512 + hc];
            float hr = acc[0][ci][j] + br;
            float hi = acc[1][ci][j] + bz;
            float hn = acc[2][ci][j] + bn;
            float hprev = hfp[(size_t)bb * 512 + hc];
            float r = 1.f / (1.f + __expf(-(ir + hr + fr)));
            float z = 1.f / (1.f + __expf(-(ii + hi + fi)));
            float n = tanhf(inn + r * hn);
            float hy = n + z * (hprev - n);
            hfp_n[(size_t)bb * 512 + hc] = hy;
            hbf_n[(size_t)bb * 512 + hc] = f2bf(hy);
            out[(size_t)bb * 64 * 512 + (size_t)t * 512 + hc] = hy;
            if (t == 63) hT[(size_t)bb * 512 + hc] = hy;
        }
    }
}

// ---------------- host launcher ----------------

extern "C" void kernel_launch(void* const* d_in, const int* in_sizes, int n_in,
                              void* d_out, int out_size, void* d_ws, size_t ws_size,
                              hipStream_t stream) {
    (void)in_sizes; (void)n_in; (void)out_size; (void)ws_size;

    const float* x0  = (const float*)d_in[0];
    const float* x1  = (const float*)d_in[1];
    const float* wa0 = (const float*)d_in[2];
    const float* wb0 = (const float*)d_in[3];
    const float* wc0 = (const float*)d_in[4];
    const float* b0  = (const float*)d_in[5];
    const float* wa1 = (const float*)d_in[6];
    const float* wb1 = (const float*)d_in[7];
    const float* wc1 = (const float*)d_in[8];
    const float* b1  = (const float*)d_in[9];
    const float* iw1 = (const float*)d_in[10];
    const float* ib1 = (const float*)d_in[11];
    const float* whh = (const float*)d_in[12];
    const float* bhh = (const float*)d_in[13];

    float* out = (float*)d_out;                  // [128,64,512]
    float* hT  = out + (size_t)128 * 64 * 512;   // [128,512]

    char* w = (char*)d_ws;
    auto alloc = [&](size_t bytes) {
        char* p = w;
        w += (bytes + 255) & ~(size_t)255;
        return p;
    };
    unsigned short* x1bf = (unsigned short*)alloc((size_t)8192 * 2048 * 2);
    unsigned short* x0bf = (unsigned short*)alloc((size_t)8192 * 1536 * 2);
    unsigned short* wih  = (unsigned short*)alloc((size_t)1536 * 2048 * 2);
    unsigned short* wfh  = (unsigned short*)alloc((size_t)1024 * 1536 * 2);
    unsigned short* wab0 = (unsigned short*)alloc((size_t)1024 * 512 * 2);
    unsigned short* wab1 = (unsigned short*)alloc((size_t)1024 * 512 * 2);
    unsigned short* wc0T = (unsigned short*)alloc((size_t)1536 * 512 * 2);
    unsigned short* wc1T = (unsigned short*)alloc((size_t)2048 * 512 * 2);
    unsigned short* whhb = (unsigned short*)alloc((size_t)1536 * 512 * 2);
    float* bih = (float*)alloc(1536 * 4);
    unsigned short* hbf = (unsigned short*)alloc((size_t)2 * 65536 * 2);
    float* hfp = (float*)alloc((size_t)2 * 65536 * 4);
    float* gi  = (float*)alloc((size_t)8192 * 1536 * 4);
    float* gf  = (float*)alloc((size_t)8192 * 1024 * 4);
    // total ~160.3 MB of d_ws

    // conversions
    cvt_bf16_kernel<<<2048, 256, 0, stream>>>(x1, x1bf, (8192 * 2048) / 8);
    cvt_bf16_kernel<<<2048, 256, 0, stream>>>(x0, x0bf, (8192 * 1536) / 8);
    wab_kernel<<<256, 256, 0, stream>>>(wa0, wb0, wab0, (1024 * 512) / 8);
    wab_kernel<<<256, 256, 0, stream>>>(wa1, wb1, wab1, (1024 * 512) / 8);
    wcT_kernel<<<768, 256, 0, stream>>>(wc0, wc0T, 1536);
    wcT_kernel<<<1024, 256, 0, stream>>>(wc1, wc1T, 2048);
    cvt_bf16_kernel<<<384, 256, 0, stream>>>(whh, whhb, (1536 * 512) / 8);
    cvt_bf16_kernel<<<512, 256, 0, stream>>>(iw1, wih + (size_t)1024 * 2048, (512 * 2048) / 8);
    bih_kernel<<<6, 256, 0, stream>>>(b1, ib1, bih);

    // weight GEMMs: w_fh[1024,1536], w_ih[0:1024,2048]
    gemm_nt_kernel<unsigned short, false><<<dim3(8, 12), 256, 0, stream>>>(
        wab0, wc0T, wfh, nullptr, 512, 1536);
    gemm_nt_kernel<unsigned short, false><<<dim3(8, 16), 256, 0, stream>>>(
        wab1, wc1T, wih, nullptr, 512, 2048);

    // big projections: gi[8192,1536], gf[8192,1024]
    gemm_nt_kernel<float, true><<<dim3(64, 12), 256, 0, stream>>>(
        x1bf, wih, gi, bih, 2048, 1536);
    gemm_nt_kernel<float, true><<<dim3(64, 8), 256, 0, stream>>>(
        x0bf, wfh, gf, b0, 1536, 1024);

    // scan
    hinit_kernel<<<256, 256, 0, stream>>>(hbf, hfp);
    for (int t = 0; t < 64; ++t) {
        int p = t & 1;
        gru_step_kernel<<<dim3(8, 16), 64, 0, stream>>>(
            hbf + (size_t)p * 65536, hfp + (size_t)p * 65536,
            hbf + (size_t)(p ^ 1) * 65536, hfp + (size_t)(p ^ 1) * 65536,
            whhb, bhh, gi, gf, out, hT, t);
    }
}